// Round 2
// baseline (10049.680 us; speedup 1.0000x reference)
//
#include <hip/hip_runtime.h>
#include <math.h>

// MultiRNNCell: 2-layer LSTM-imputation scan. B=64, T=128, D=256, H=1024.
// R1: single persistent kernel, 128 timesteps in-kernel, manual device-scope
// grid barrier. 144 blocks x 256 thr, 120KB static LDS -> 1 block/CU, all
// co-resident (144 <= 256 CUs). Weights live in LDS in MFMA fragment order.
// Algebraic reductions kept from R0: dead forget gate (3/4 gates), layer1
// weight fold W1 = Wih1+Whh1.

#define B_ 64
#define T_ 128
#define D_ 256
#define H_ 1024
#define G_ 4096

#define NL0 64          // layer-0 blocks (16 units each)
#define NL1 64          // layer-1 blocks
#define NEST 16         // est blocks (16 d-cols each)
#define NBLK (NL0 + NL1 + NEST)   // 144

#define KS0 40          // layer0 ksteps: 8 (imputed, D=256) + 32 (h, H=1024)
#define KS1 32          // layer1 ksteps (H=1024)
#define KSE 32          // est ksteps (H=1024)

typedef __attribute__((ext_vector_type(8))) short short8;   // 8 bf16
typedef __attribute__((ext_vector_type(4))) float floatx4;  // MFMA C/D

__device__ __forceinline__ unsigned short f2bf(float x) {
    union { float f; unsigned u; } v; v.f = x;
    unsigned r = v.u + 0x7fffu + ((v.u >> 16) & 1u);  // RNE
    return (unsigned short)(r >> 16);
}
__device__ __forceinline__ float sigmoidf_(float x) { return 1.0f / (1.0f + expf(-x)); }

// ---------------- prep kernels ----------------
__global__ void k_cvt(const float* __restrict__ s, unsigned short* __restrict__ d, int n) {
    int i = blockIdx.x * 256 + threadIdx.x;
    if (i < n) d[i] = f2bf(s[i]);
}
__global__ void k_addcvt(const float* __restrict__ a, const float* __restrict__ b,
                         unsigned short* __restrict__ d, int n) {
    int i = blockIdx.x * 256 + threadIdx.x;
    if (i < n) d[i] = f2bf(a[i] + b[i]);
}
__global__ void k_addf(const float* __restrict__ a, const float* __restrict__ b,
                       float* __restrict__ d, int n) {
    int i = blockIdx.x * 256 + threadIdx.x;
    if (i < n) d[i] = a[i] + b[i];
}

// ---------------- device-scope grid barrier ----------------
__device__ __forceinline__ void gbar(unsigned* cnt, unsigned target) {
    __threadfence();          // per-wave: drain stores, flush to device scope
    __syncthreads();
    if (threadIdx.x == 0) {
        __hip_atomic_fetch_add(cnt, 1u, __ATOMIC_RELEASE, __HIP_MEMORY_SCOPE_AGENT);
        while (__hip_atomic_load(cnt, __ATOMIC_ACQUIRE, __HIP_MEMORY_SCOPE_AGENT) < target)
            __builtin_amdgcn_s_sleep(2);
    }
    __syncthreads();
}

// ---------------- fused persistent kernel ----------------
__global__ __launch_bounds__(256, 1) void k_fused(
    const unsigned short* __restrict__ Wih0bf, const unsigned short* __restrict__ Whh0bf,
    const unsigned short* __restrict__ W1bf,   const unsigned short* __restrict__ Woutbf,
    const float* __restrict__ b0c, const float* __restrict__ b1c, const float* __restrict__ bout,
    const float* __restrict__ X, const float* __restrict__ Mm,
    unsigned short* __restrict__ hbf, unsigned short* __restrict__ h0bf,
    unsigned short* __restrict__ impbf, float* __restrict__ out,
    unsigned* __restrict__ barcnt)
{
    // fragment-order weight store: [fragIdx][lane][8 bf16]; ds_read_b128
    // lane-consecutive 16B -> conflict-free. layer0: 3*40 frags = 120KB.
    __shared__ unsigned short ldsW[3 * KS0 * 64 * 8];

    const int tid  = threadIdx.x;
    const int lane = tid & 63;
    const int wv   = tid >> 6;       // wave id = m-tile (16 batch rows)
    const int r16  = lane & 15, q = lane >> 4;
    const int bx   = blockIdx.x;
    const int m0   = wv * 16;
    const unsigned short* lfrag = ldsW + lane * 8;   // + fragIdx*512

    // ---- one-time: rearrange weights into LDS fragment order ----
    if (bx < NL0) {
        int n0 = bx * 16;
        for (int idx = wv; idx < 3 * KS0; idx += 4) {
            int gi = idx / KS0, k = idx % KS0;
            int grow = (gi == 0) ? 0 : (gi == 1 ? 2 * H_ : 3 * H_);
            const unsigned short* src = (k < 8)
                ? Wih0bf + (grow + n0 + r16) * D_ + k * 32 + q * 8
                : Whh0bf + (grow + n0 + r16) * H_ + (k - 8) * 32 + q * 8;
            *(short8*)(ldsW + ((size_t)idx * 64 + lane) * 8) = *(const short8*)src;
        }
    } else if (bx < NL0 + NL1) {
        int n0 = (bx - NL0) * 16;
        for (int idx = wv; idx < 3 * KS1; idx += 4) {
            int gi = idx / KS1, k = idx % KS1;
            int grow = (gi == 0) ? 0 : (gi == 1 ? 2 * H_ : 3 * H_);
            *(short8*)(ldsW + ((size_t)idx * 64 + lane) * 8) =
                *(const short8*)(W1bf + (grow + n0 + r16) * H_ + k * 32 + q * 8);
        }
    } else {
        int d0 = (bx - NL0 - NL1) * 16;
        for (int idx = wv; idx < KSE; idx += 4)
            *(short8*)(ldsW + ((size_t)idx * 64 + lane) * 8) =
                *(const short8*)(Woutbf + (d0 + r16) * H_ + idx * 32 + q * 8);
    }
    __syncthreads();

    unsigned barno = 0;
    floatx4 ai = {0.f,0.f,0.f,0.f}, ag = ai, ao = ai;

    for (int t = 0; t < T_; ++t) {
        // ---------- P1: est+impute (est blocks) | layer0 h-part (l0 blocks) ----------
        if (bx < NL0) {
            ai = (floatx4){0.f,0.f,0.f,0.f}; ag = ai; ao = ai;
            const unsigned short* aB = hbf + (m0 + r16) * H_ + q * 8;
            #pragma unroll 4
            for (int k = 8; k < KS0; ++k) {
                short8 a = *(const short8*)(aB + (k - 8) * 32);
                ai = __builtin_amdgcn_mfma_f32_16x16x32_bf16(a, *(const short8*)(lfrag + (0*KS0 + k)*512), ai, 0,0,0);
                ag = __builtin_amdgcn_mfma_f32_16x16x32_bf16(a, *(const short8*)(lfrag + (1*KS0 + k)*512), ag, 0,0,0);
                ao = __builtin_amdgcn_mfma_f32_16x16x32_bf16(a, *(const short8*)(lfrag + (2*KS0 + k)*512), ao, 0,0,0);
            }
        } else if (bx >= NL0 + NL1) {
            int d0 = (bx - NL0 - NL1) * 16;
            floatx4 acc = {0.f,0.f,0.f,0.f};
            const unsigned short* aB = hbf + (m0 + r16) * H_ + q * 8;
            #pragma unroll 4
            for (int k = 0; k < KSE; ++k) {
                short8 a = *(const short8*)(aB + k * 32);
                acc = __builtin_amdgcn_mfma_f32_16x16x32_bf16(a, *(const short8*)(lfrag + k*512), acc, 0,0,0);
            }
            int dd = d0 + r16;
            float bo_ = bout[dd];
            #pragma unroll
            for (int r = 0; r < 4; r++) {
                int bb = m0 + q * 4 + r;
                float est = acc[r] + bo_;
                float x = X [(bb * T_ + t) * D_ + dd];
                float m = Mm[(bb * T_ + t) * D_ + dd];
                impbf[bb * D_ + dd] = f2bf(m * x + (1.0f - m) * est);
                if (t >= 1) out[(bb * T_ + (t - 1)) * D_ + dd] = est;
            }
        }
        gbar(barcnt, ++barno * NBLK);

        // ---------- P2: layer0 imputed-part + activation -> h0 ----------
        if (bx < NL0) {
            const unsigned short* aB = impbf + (m0 + r16) * D_ + q * 8;
            #pragma unroll
            for (int k = 0; k < 8; ++k) {
                short8 a = *(const short8*)(aB + k * 32);
                ai = __builtin_amdgcn_mfma_f32_16x16x32_bf16(a, *(const short8*)(lfrag + (0*KS0 + k)*512), ai, 0,0,0);
                ag = __builtin_amdgcn_mfma_f32_16x16x32_bf16(a, *(const short8*)(lfrag + (1*KS0 + k)*512), ag, 0,0,0);
                ao = __builtin_amdgcn_mfma_f32_16x16x32_bf16(a, *(const short8*)(lfrag + (2*KS0 + k)*512), ao, 0,0,0);
            }
            int n = bx * 16 + r16;
            float bi = b0c[n], bg = b0c[2 * H_ + n], bo = b0c[3 * H_ + n];
            #pragma unroll
            for (int r = 0; r < 4; r++) {
                int bb = m0 + q * 4 + r;
                float c = sigmoidf_(ai[r] + bi) * tanhf(ag[r] + bg);
                float h = sigmoidf_(ao[r] + bo) * tanhf(c);
                h0bf[bb * H_ + n] = f2bf(h);
            }
        }
        gbar(barcnt, ++barno * NBLK);

        // ---------- P3: layer1 -> h ----------
        if (bx >= NL0 && bx < NL0 + NL1) {
            int n0 = (bx - NL0) * 16;
            floatx4 li = {0.f,0.f,0.f,0.f}, lg = li, lo = li;
            const unsigned short* aB = h0bf + (m0 + r16) * H_ + q * 8;
            #pragma unroll 4
            for (int k = 0; k < KS1; ++k) {
                short8 a = *(const short8*)(aB + k * 32);
                li = __builtin_amdgcn_mfma_f32_16x16x32_bf16(a, *(const short8*)(lfrag + (0*KS1 + k)*512), li, 0,0,0);
                lg = __builtin_amdgcn_mfma_f32_16x16x32_bf16(a, *(const short8*)(lfrag + (1*KS1 + k)*512), lg, 0,0,0);
                lo = __builtin_amdgcn_mfma_f32_16x16x32_bf16(a, *(const short8*)(lfrag + (2*KS1 + k)*512), lo, 0,0,0);
            }
            int n = n0 + r16;
            float bi = b1c[n], bg = b1c[2 * H_ + n], bo = b1c[3 * H_ + n];
            #pragma unroll
            for (int r = 0; r < 4; r++) {
                int bb = m0 + q * 4 + r;
                float c = sigmoidf_(li[r] + bi) * tanhf(lg[r] + bg);
                float h = sigmoidf_(lo[r] + bo) * tanhf(c);
                hbf[bb * H_ + n] = f2bf(h);
                if (t == T_ - 1) out[(size_t)B_ * T_ * D_ + bb * H_ + n] = h;
            }
        }
        gbar(barcnt, ++barno * NBLK);
    }

    // ---------- final projection: est from h(T-1) -> out[:, T-1, :] ----------
    if (bx >= NL0 + NL1) {
        int d0 = (bx - NL0 - NL1) * 16;
        floatx4 acc = {0.f,0.f,0.f,0.f};
        const unsigned short* aB = hbf + (m0 + r16) * H_ + q * 8;
        #pragma unroll 4
        for (int k = 0; k < KSE; ++k) {
            short8 a = *(const short8*)(aB + k * 32);
            acc = __builtin_amdgcn_mfma_f32_16x16x32_bf16(a, *(const short8*)(lfrag + k*512), acc, 0,0,0);
        }
        int dd = d0 + r16;
        float bo_ = bout[dd];
        #pragma unroll
        for (int r = 0; r < 4; r++) {
            int bb = m0 + q * 4 + r;
            out[(bb * T_ + (T_ - 1)) * D_ + dd] = acc[r] + bo_;
        }
    }
}

extern "C" void kernel_launch(void* const* d_in, const int* in_sizes, int n_in,
                              void* d_out, int out_size, void* d_ws, size_t ws_size,
                              hipStream_t stream) {
    const float* X    = (const float*)d_in[0];
    const float* Mm   = (const float*)d_in[1];
    const float* Wih0 = (const float*)d_in[2];
    const float* Whh0 = (const float*)d_in[3];
    const float* bih0 = (const float*)d_in[4];
    const float* bhh0 = (const float*)d_in[5];
    const float* Wih1 = (const float*)d_in[6];
    const float* Whh1 = (const float*)d_in[7];
    const float* bih1 = (const float*)d_in[8];
    const float* bhh1 = (const float*)d_in[9];
    const float* Wout = (const float*)d_in[10];
    const float* bout = (const float*)d_in[11];
    float* out = (float*)d_out;

    char* ws = (char*)d_ws;
    size_t off = 0;
    auto alloc = [&](size_t bytes) { char* p = ws + off; off = (off + bytes + 255) & ~(size_t)255; return p; };
    unsigned*       barcnt = (unsigned*)alloc(256);
    unsigned short* hbf    = (unsigned short*)alloc(B_ * H_ * 2);
    unsigned short* h0bf   = (unsigned short*)alloc(B_ * H_ * 2);
    unsigned short* impbf  = (unsigned short*)alloc(B_ * D_ * 2);
    unsigned short* Wih0bf = (unsigned short*)alloc((size_t)G_ * D_ * 2);
    unsigned short* Whh0bf = (unsigned short*)alloc((size_t)G_ * H_ * 2);
    unsigned short* W1bf   = (unsigned short*)alloc((size_t)G_ * H_ * 2);
    unsigned short* Woutbf = (unsigned short*)alloc((size_t)D_ * H_ * 2);
    float*          b0c    = (float*)alloc(G_ * 4);
    float*          b1c    = (float*)alloc(G_ * 4);

    hipMemsetAsync(barcnt, 0, 256, stream);
    hipMemsetAsync(hbf, 0, B_ * H_ * 2, stream);

    {
        int n;
        n = G_ * D_; k_cvt   <<<(n + 255) / 256, 256, 0, stream>>>(Wih0, Wih0bf, n);
        n = G_ * H_; k_cvt   <<<(n + 255) / 256, 256, 0, stream>>>(Whh0, Whh0bf, n);
        n = G_ * H_; k_addcvt<<<(n + 255) / 256, 256, 0, stream>>>(Wih1, Whh1, W1bf, n);
        n = D_ * H_; k_cvt   <<<(n + 255) / 256, 256, 0, stream>>>(Wout, Woutbf, n);
        n = G_;      k_addf  <<<(n + 255) / 256, 256, 0, stream>>>(bih0, bhh0, b0c, n);
        n = G_;      k_addf  <<<(n + 255) / 256, 256, 0, stream>>>(bih1, bhh1, b1c, n);
    }

    k_fused<<<NBLK, 256, 0, stream>>>(Wih0bf, Whh0bf, W1bf, Woutbf, b0c, b1c, bout,
                                      X, Mm, hbf, h0bf, impbf, out, barcnt);
}

// Round 4
// 3829.858 us; speedup vs baseline: 2.6240x; 2.6240x over previous
//
#include <hip/hip_runtime.h>
#include <math.h>

// MultiRNNCell: 2-layer LSTM-imputation scan. B=64, T=128, D=256, H=1024.
// R3 (= R2 with fence builtin fixed): persistent kernel, producer->consumer
// flag sync (no global barrier).
//  - per-producer-block monotonic step flags, contiguous 4B each
//  - RELAXED agent-scope polling (no buffer_inv per iteration), single ACQUIRE
//    fence after success (+ periodic safety fence vs stale reads)
//  - only true deps sync: est->l0 (impbf), l0->l1 (h0bf), l1->{est,l0} (hbf)
// 144 blocks x 256 thr, 120KB LDS -> 1 block/CU, all co-resident.
// Weights LDS-resident in MFMA fragment order. Dead forget gate removed;
// layer1 weight fold W1 = Wih1+Whh1.

#define B_ 64
#define T_ 128
#define D_ 256
#define H_ 1024
#define G_ 4096

#define NL0 64
#define NL1 64
#define NEST 16
#define NBLK (NL0 + NL1 + NEST)   // 144

#define KS0 40          // layer0 ksteps: 8 (imputed, D=256) + 32 (h, H=1024)
#define KS1 32          // layer1 ksteps (H=1024)
#define KSE 32          // est ksteps (H=1024)

typedef __attribute__((ext_vector_type(8))) short short8;   // 8 bf16
typedef __attribute__((ext_vector_type(4))) float floatx4;  // MFMA C/D

__device__ __forceinline__ unsigned short f2bf(float x) {
    union { float f; unsigned u; } v; v.f = x;
    unsigned r = v.u + 0x7fffu + ((v.u >> 16) & 1u);  // RNE
    return (unsigned short)(r >> 16);
}
__device__ __forceinline__ float sigmoidf_(float x) { return 1.0f / (1.0f + expf(-x)); }

// ---------------- prep kernels ----------------
__global__ void k_cvt(const float* __restrict__ s, unsigned short* __restrict__ d, int n) {
    int i = blockIdx.x * 256 + threadIdx.x;
    if (i < n) d[i] = f2bf(s[i]);
}
__global__ void k_addcvt(const float* __restrict__ a, const float* __restrict__ b,
                         unsigned short* __restrict__ d, int n) {
    int i = blockIdx.x * 256 + threadIdx.x;
    if (i < n) d[i] = f2bf(a[i] + b[i]);
}
__global__ void k_addf(const float* __restrict__ a, const float* __restrict__ b,
                       float* __restrict__ d, int n) {
    int i = blockIdx.x * 256 + threadIdx.x;
    if (i < n) d[i] = a[i] + b[i];
}

// ---------------- producer/consumer sync ----------------
// Wait until flags[0..P) all >= target. Wave 0 polls (coalesced, relaxed
// agent loads -> no per-iteration cache invalidate); one acquire fence on
// success. Periodic acquire fence every 1024 spins = stale-read insurance.
__device__ __forceinline__ void wait_flags(int* flags, int P, int target) {
    if (threadIdx.x < 64) {
        int l = threadIdx.x;
        if (l < P) {
            int spins = 0;
            while (__hip_atomic_load(flags + l, __ATOMIC_RELAXED,
                                     __HIP_MEMORY_SCOPE_AGENT) < target) {
                __builtin_amdgcn_s_sleep(1);
                if ((++spins & 1023) == 0)
                    __builtin_amdgcn_fence(__ATOMIC_ACQUIRE, "agent");
            }
        }
        __builtin_amdgcn_fence(__ATOMIC_ACQUIRE, "agent");
    }
    __syncthreads();
}
// All waves' stores drained by __syncthreads (full waitcnt before s_barrier),
// then one thread: release fence (L2 writeback) + relaxed flag store. No RMW.
__device__ __forceinline__ void signal_flag(int* flag, int val) {
    __syncthreads();
    if (threadIdx.x == 0) {
        __builtin_amdgcn_fence(__ATOMIC_RELEASE, "agent");
        __hip_atomic_store(flag, val, __ATOMIC_RELAXED, __HIP_MEMORY_SCOPE_AGENT);
    }
}

// ---------------- fused persistent kernel ----------------
__global__ __launch_bounds__(256, 1) void k_fused(
    const unsigned short* __restrict__ Wih0bf, const unsigned short* __restrict__ Whh0bf,
    const unsigned short* __restrict__ W1bf,   const unsigned short* __restrict__ Woutbf,
    const float* __restrict__ b0c, const float* __restrict__ b1c, const float* __restrict__ bout,
    const float* __restrict__ X, const float* __restrict__ Mm,
    unsigned short* __restrict__ hbf, unsigned short* __restrict__ h0bf,
    unsigned short* __restrict__ impbf, float* __restrict__ out,
    int* __restrict__ flagsL1, int* __restrict__ flagsEst, int* __restrict__ flagsL0)
{
    // weight fragments: [fragIdx][lane][8 bf16]; ds_read_b128 conflict-free
    __shared__ unsigned short ldsW[3 * KS0 * 64 * 8];   // 120 KB (l0 blocks)

    const int tid  = threadIdx.x;
    const int lane = tid & 63;
    const int wv   = tid >> 6;       // wave id = m-tile (16 batch rows)
    const int r16  = lane & 15, q = lane >> 4;
    const int bx   = blockIdx.x;
    const int m0   = wv * 16;
    const unsigned short* lfrag = ldsW + lane * 8;   // + fragIdx*512

    // ---- one-time: rearrange weights into LDS fragment order ----
    if (bx < NL0) {
        int n0 = bx * 16;
        for (int idx = wv; idx < 3 * KS0; idx += 4) {
            int gi = idx / KS0, k = idx % KS0;
            int grow = (gi == 0) ? 0 : (gi == 1 ? 2 * H_ : 3 * H_);
            const unsigned short* src = (k < 8)
                ? Wih0bf + (grow + n0 + r16) * D_ + k * 32 + q * 8
                : Whh0bf + (grow + n0 + r16) * H_ + (k - 8) * 32 + q * 8;
            *(short8*)(ldsW + ((size_t)idx * 64 + lane) * 8) = *(const short8*)src;
        }
    } else if (bx < NL0 + NL1) {
        int n0 = (bx - NL0) * 16;
        for (int idx = wv; idx < 3 * KS1; idx += 4) {
            int gi = idx / KS1, k = idx % KS1;
            int grow = (gi == 0) ? 0 : (gi == 1 ? 2 * H_ : 3 * H_);
            *(short8*)(ldsW + ((size_t)idx * 64 + lane) * 8) =
                *(const short8*)(W1bf + (grow + n0 + r16) * H_ + k * 32 + q * 8);
        }
    } else {
        int d0 = (bx - NL0 - NL1) * 16;
        for (int idx = wv; idx < KSE; idx += 4)
            *(short8*)(ldsW + ((size_t)idx * 64 + lane) * 8) =
                *(const short8*)(Woutbf + (d0 + r16) * H_ + idx * 32 + q * 8);
    }
    __syncthreads();

    if (bx < NL0) {
        // =============== layer-0 blocks ===============
        const int n = bx * 16 + r16;
        const float bi = b0c[n], bg = b0c[2 * H_ + n], bo = b0c[3 * H_ + n];
        for (int t = 0; t < T_; ++t) {
            wait_flags(flagsL1, NL1, t);              // need h(t-1)
            floatx4 ai = {0.f,0.f,0.f,0.f}, ag = ai, ao = ai;
            {   // h-part (overlaps est blocks' work)
                const unsigned short* aB = hbf + (m0 + r16) * H_ + q * 8;
                #pragma unroll 4
                for (int k = 8; k < KS0; ++k) {
                    short8 a = *(const short8*)(aB + (k - 8) * 32);
                    ai = __builtin_amdgcn_mfma_f32_16x16x32_bf16(a, *(const short8*)(lfrag + (0*KS0 + k)*512), ai, 0,0,0);
                    ag = __builtin_amdgcn_mfma_f32_16x16x32_bf16(a, *(const short8*)(lfrag + (1*KS0 + k)*512), ag, 0,0,0);
                    ao = __builtin_amdgcn_mfma_f32_16x16x32_bf16(a, *(const short8*)(lfrag + (2*KS0 + k)*512), ao, 0,0,0);
                }
            }
            wait_flags(flagsEst, NEST, t + 1);        // need imputed(t)
            {   // imputed part + activation
                const unsigned short* aB = impbf + (m0 + r16) * D_ + q * 8;
                #pragma unroll
                for (int k = 0; k < 8; ++k) {
                    short8 a = *(const short8*)(aB + k * 32);
                    ai = __builtin_amdgcn_mfma_f32_16x16x32_bf16(a, *(const short8*)(lfrag + (0*KS0 + k)*512), ai, 0,0,0);
                    ag = __builtin_amdgcn_mfma_f32_16x16x32_bf16(a, *(const short8*)(lfrag + (1*KS0 + k)*512), ag, 0,0,0);
                    ao = __builtin_amdgcn_mfma_f32_16x16x32_bf16(a, *(const short8*)(lfrag + (2*KS0 + k)*512), ao, 0,0,0);
                }
                #pragma unroll
                for (int r = 0; r < 4; r++) {
                    int bb = m0 + q * 4 + r;
                    float c = sigmoidf_(ai[r] + bi) * tanhf(ag[r] + bg);
                    float h = sigmoidf_(ao[r] + bo) * tanhf(c);
                    h0bf[bb * H_ + n] = f2bf(h);
                }
            }
            signal_flag(&flagsL0[bx], t + 1);
        }
    } else if (bx < NL0 + NL1) {
        // =============== layer-1 blocks ===============
        const int j = bx - NL0;
        const int n = j * 16 + r16;
        const float bi = b1c[n], bg = b1c[2 * H_ + n], bo = b1c[3 * H_ + n];
        for (int t = 0; t < T_; ++t) {
            wait_flags(flagsL0, NL0, t + 1);          // need h0(t)
            floatx4 li = {0.f,0.f,0.f,0.f}, lg = li, lo = li;
            const unsigned short* aB = h0bf + (m0 + r16) * H_ + q * 8;
            #pragma unroll 4
            for (int k = 0; k < KS1; ++k) {
                short8 a = *(const short8*)(aB + k * 32);
                li = __builtin_amdgcn_mfma_f32_16x16x32_bf16(a, *(const short8*)(lfrag + (0*KS1 + k)*512), li, 0,0,0);
                lg = __builtin_amdgcn_mfma_f32_16x16x32_bf16(a, *(const short8*)(lfrag + (1*KS1 + k)*512), lg, 0,0,0);
                lo = __builtin_amdgcn_mfma_f32_16x16x32_bf16(a, *(const short8*)(lfrag + (2*KS1 + k)*512), lo, 0,0,0);
            }
            #pragma unroll
            for (int r = 0; r < 4; r++) {
                int bb = m0 + q * 4 + r;
                float c = sigmoidf_(li[r] + bi) * tanhf(lg[r] + bg);
                float h = sigmoidf_(lo[r] + bo) * tanhf(c);
                hbf[bb * H_ + n] = f2bf(h);
                if (t == T_ - 1) out[(size_t)B_ * T_ * D_ + bb * H_ + n] = h;
            }
            signal_flag(&flagsL1[j], t + 1);
        }
    } else {
        // =============== est/impute blocks ===============
        const int e  = bx - NL0 - NL1;
        const int dd = e * 16 + r16;
        const float bo_ = bout[dd];
        for (int t = 0; t < T_; ++t) {
            wait_flags(flagsL1, NL1, t);              // need h(t-1)
            floatx4 acc = {0.f,0.f,0.f,0.f};
            const unsigned short* aB = hbf + (m0 + r16) * H_ + q * 8;
            #pragma unroll 4
            for (int k = 0; k < KSE; ++k) {
                short8 a = *(const short8*)(aB + k * 32);
                acc = __builtin_amdgcn_mfma_f32_16x16x32_bf16(a, *(const short8*)(lfrag + k*512), acc, 0,0,0);
            }
            #pragma unroll
            for (int r = 0; r < 4; r++) {
                int bb = m0 + q * 4 + r;
                float est = acc[r] + bo_;
                float x = X [(bb * T_ + t) * D_ + dd];
                float m = Mm[(bb * T_ + t) * D_ + dd];
                impbf[bb * D_ + dd] = f2bf(m * x + (1.0f - m) * est);
                if (t >= 1) out[(bb * T_ + (t - 1)) * D_ + dd] = est;
            }
            signal_flag(&flagsEst[e], t + 1);
        }
        // final projection: est from h(T-1) -> out[:, T-1, :]
        wait_flags(flagsL1, NL1, T_);
        floatx4 acc = {0.f,0.f,0.f,0.f};
        const unsigned short* aB = hbf + (m0 + r16) * H_ + q * 8;
        #pragma unroll 4
        for (int k = 0; k < KSE; ++k) {
            short8 a = *(const short8*)(aB + k * 32);
            acc = __builtin_amdgcn_mfma_f32_16x16x32_bf16(a, *(const short8*)(lfrag + k*512), acc, 0,0,0);
        }
        #pragma unroll
        for (int r = 0; r < 4; r++) {
            int bb = m0 + q * 4 + r;
            out[(bb * T_ + (T_ - 1)) * D_ + dd] = acc[r] + bo_;
        }
    }
}

extern "C" void kernel_launch(void* const* d_in, const int* in_sizes, int n_in,
                              void* d_out, int out_size, void* d_ws, size_t ws_size,
                              hipStream_t stream) {
    const float* X    = (const float*)d_in[0];
    const float* Mm   = (const float*)d_in[1];
    const float* Wih0 = (const float*)d_in[2];
    const float* Whh0 = (const float*)d_in[3];
    const float* bih0 = (const float*)d_in[4];
    const float* bhh0 = (const float*)d_in[5];
    const float* Wih1 = (const float*)d_in[6];
    const float* Whh1 = (const float*)d_in[7];
    const float* bih1 = (const float*)d_in[8];
    const float* bhh1 = (const float*)d_in[9];
    const float* Wout = (const float*)d_in[10];
    const float* bout = (const float*)d_in[11];
    float* out = (float*)d_out;

    char* ws = (char*)d_ws;
    size_t off = 0;
    auto alloc = [&](size_t bytes) { char* p = ws + off; off = (off + bytes + 255) & ~(size_t)255; return p; };
    int*            flagsL1  = (int*)alloc(NL1 * 4);
    int*            flagsEst = (int*)alloc(NEST * 4);
    int*            flagsL0  = (int*)alloc(NL0 * 4);
    unsigned short* hbf    = (unsigned short*)alloc(B_ * H_ * 2);
    unsigned short* h0bf   = (unsigned short*)alloc(B_ * H_ * 2);
    unsigned short* impbf  = (unsigned short*)alloc(B_ * D_ * 2);
    unsigned short* Wih0bf = (unsigned short*)alloc((size_t)G_ * D_ * 2);
    unsigned short* Whh0bf = (unsigned short*)alloc((size_t)G_ * H_ * 2);
    unsigned short* W1bf   = (unsigned short*)alloc((size_t)G_ * H_ * 2);
    unsigned short* Woutbf = (unsigned short*)alloc((size_t)D_ * H_ * 2);
    float*          b0c    = (float*)alloc(G_ * 4);
    float*          b1c    = (float*)alloc(G_ * 4);

    (void)hipMemsetAsync(flagsL1, 0, (char*)hbf - (char*)flagsL1, stream);  // all flags
    (void)hipMemsetAsync(hbf, 0, B_ * H_ * 2, stream);

    {
        int n;
        n = G_ * D_; k_cvt   <<<(n + 255) / 256, 256, 0, stream>>>(Wih0, Wih0bf, n);
        n = G_ * H_; k_cvt   <<<(n + 255) / 256, 256, 0, stream>>>(Whh0, Whh0bf, n);
        n = G_ * H_; k_addcvt<<<(n + 255) / 256, 256, 0, stream>>>(Wih1, Whh1, W1bf, n);
        n = D_ * H_; k_cvt   <<<(n + 255) / 256, 256, 0, stream>>>(Wout, Woutbf, n);
        n = G_;      k_addf  <<<(n + 255) / 256, 256, 0, stream>>>(bih0, bhh0, b0c, n);
        n = G_;      k_addf  <<<(n + 255) / 256, 256, 0, stream>>>(bih1, bhh1, b1c, n);
    }

    k_fused<<<NBLK, 256, 0, stream>>>(Wih0bf, Whh0bf, W1bf, Woutbf, b0c, b1c, bout,
                                      X, Mm, hbf, h0bf, impbf, out,
                                      flagsL1, flagsEst, flagsL0);
}

// Round 5
// 3178.006 us; speedup vs baseline: 3.1623x; 1.2051x over previous
//
#include <hip/hip_runtime.h>
#include <math.h>

// MultiRNNCell: 2-layer LSTM-imputation scan. B=64, T=128, D=256, H=1024.
// R4: persistent kernel, producer->consumer flag sync, FENCE-FREE producer
// path: cross-block activations written with sc0 sc1 (write-through to MALL,
// never dirty in L2) + per-wave vmcnt(0) drain -> no buffer_wbl2 at signal.
// Consumers: acquire fence (buffer_inv) + plain vectorized loads (refetch
// from MALL is the intrinsic broadcast cost, overlaps MFMA).
// est blocks prefetch X/Mm into registers before waiting.
// 144 blocks x 256 thr, 120KB LDS -> 1 block/CU, all co-resident.
// Weights LDS-resident in MFMA fragment order. Dead forget gate removed;
// layer1 weight fold W1 = Wih1+Whh1.

#define B_ 64
#define T_ 128
#define D_ 256
#define H_ 1024
#define G_ 4096

#define NL0 64
#define NL1 64
#define NEST 16
#define NBLK (NL0 + NL1 + NEST)   // 144

#define KS0 40          // layer0 ksteps: 8 (imputed, D=256) + 32 (h, H=1024)
#define KS1 32          // layer1 ksteps (H=1024)
#define KSE 32          // est ksteps (H=1024)

typedef __attribute__((ext_vector_type(8))) short short8;   // 8 bf16
typedef __attribute__((ext_vector_type(4))) float floatx4;  // MFMA C/D

__device__ __forceinline__ unsigned short f2bf(float x) {
    union { float f; unsigned u; } v; v.f = x;
    unsigned r = v.u + 0x7fffu + ((v.u >> 16) & 1u);  // RNE
    return (unsigned short)(r >> 16);
}
__device__ __forceinline__ float sigmoidf_(float x) { return 1.0f / (1.0f + expf(-x)); }

// write-through 2B store to the MALL coherence point (bypasses L1+L2)
__device__ __forceinline__ void st_short_sc(unsigned short* p, unsigned v) {
    asm volatile("global_store_short %0, %1, off sc0 sc1"
                 :: "v"(p), "v"(v) : "memory");
}
// per-wave drain: sc1 store acks come from the coherence point
__device__ __forceinline__ void wave_drain() {
    asm volatile("s_waitcnt vmcnt(0)" ::: "memory");
}

// ---------------- prep kernels ----------------
__global__ void k_cvt(const float* __restrict__ s, unsigned short* __restrict__ d, int n) {
    int i = blockIdx.x * 256 + threadIdx.x;
    if (i < n) d[i] = f2bf(s[i]);
}
__global__ void k_addcvt(const float* __restrict__ a, const float* __restrict__ b,
                         unsigned short* __restrict__ d, int n) {
    int i = blockIdx.x * 256 + threadIdx.x;
    if (i < n) d[i] = f2bf(a[i] + b[i]);
}
__global__ void k_addf(const float* __restrict__ a, const float* __restrict__ b,
                       float* __restrict__ d, int n) {
    int i = blockIdx.x * 256 + threadIdx.x;
    if (i < n) d[i] = a[i] + b[i];
}

// ---------------- producer/consumer sync ----------------
// Wait until flags[0..P) all >= target. Wave 0 polls relaxed agent loads
// (sc1 -> always fresh from MALL, no cache maintenance per iteration);
// acquire fence (buffer_inv) once on success so subsequent PLAIN data loads
// can't hit stale L1/L2. Periodic fence = livelock insurance only.
__device__ __forceinline__ void wait_flags(int* flags, int P, int target) {
    if (threadIdx.x < 64) {
        int l = threadIdx.x;
        if (l < P) {
            int spins = 0;
            while (__hip_atomic_load(flags + l, __ATOMIC_RELAXED,
                                     __HIP_MEMORY_SCOPE_AGENT) < target) {
                __builtin_amdgcn_s_sleep(1);
                if ((++spins & 4095) == 0)
                    __builtin_amdgcn_fence(__ATOMIC_ACQUIRE, "agent");
            }
        }
        __builtin_amdgcn_fence(__ATOMIC_ACQUIRE, "agent");
    }
    __syncthreads();
}
// Producer data already at MALL (sc1 stores + per-wave vmcnt drain before the
// barrier). Flag store is relaxed agent (sc1 write-through). NO release fence.
__device__ __forceinline__ void signal_flag(int* flag, int val) {
    __syncthreads();
    if (threadIdx.x == 0)
        __hip_atomic_store(flag, val, __ATOMIC_RELAXED, __HIP_MEMORY_SCOPE_AGENT);
}

// ---------------- fused persistent kernel ----------------
__global__ __launch_bounds__(256, 1) void k_fused(
    const unsigned short* __restrict__ Wih0bf, const unsigned short* __restrict__ Whh0bf,
    const unsigned short* __restrict__ W1bf,   const unsigned short* __restrict__ Woutbf,
    const float* __restrict__ b0c, const float* __restrict__ b1c, const float* __restrict__ bout,
    const float* __restrict__ X, const float* __restrict__ Mm,
    unsigned short* __restrict__ hbf, unsigned short* __restrict__ h0bf,
    unsigned short* __restrict__ impbf, float* __restrict__ out,
    int* __restrict__ flagsL1, int* __restrict__ flagsEst, int* __restrict__ flagsL0)
{
    // weight fragments: [fragIdx][lane][8 bf16]; ds_read_b128 conflict-free
    __shared__ unsigned short ldsW[3 * KS0 * 64 * 8];   // 120 KB (l0 blocks)

    const int tid  = threadIdx.x;
    const int lane = tid & 63;
    const int wv   = tid >> 6;       // wave id = m-tile (16 batch rows)
    const int r16  = lane & 15, q = lane >> 4;
    const int bx   = blockIdx.x;
    const int m0   = wv * 16;
    const unsigned short* lfrag = ldsW + lane * 8;   // + fragIdx*512

    // ---- one-time: rearrange weights into LDS fragment order ----
    if (bx < NL0) {
        int n0 = bx * 16;
        for (int idx = wv; idx < 3 * KS0; idx += 4) {
            int gi = idx / KS0, k = idx % KS0;
            int grow = (gi == 0) ? 0 : (gi == 1 ? 2 * H_ : 3 * H_);
            const unsigned short* src = (k < 8)
                ? Wih0bf + (grow + n0 + r16) * D_ + k * 32 + q * 8
                : Whh0bf + (grow + n0 + r16) * H_ + (k - 8) * 32 + q * 8;
            *(short8*)(ldsW + ((size_t)idx * 64 + lane) * 8) = *(const short8*)src;
        }
    } else if (bx < NL0 + NL1) {
        int n0 = (bx - NL0) * 16;
        for (int idx = wv; idx < 3 * KS1; idx += 4) {
            int gi = idx / KS1, k = idx % KS1;
            int grow = (gi == 0) ? 0 : (gi == 1 ? 2 * H_ : 3 * H_);
            *(short8*)(ldsW + ((size_t)idx * 64 + lane) * 8) =
                *(const short8*)(W1bf + (grow + n0 + r16) * H_ + k * 32 + q * 8);
        }
    } else {
        int d0 = (bx - NL0 - NL1) * 16;
        for (int idx = wv; idx < KSE; idx += 4)
            *(short8*)(ldsW + ((size_t)idx * 64 + lane) * 8) =
                *(const short8*)(Woutbf + (d0 + r16) * H_ + idx * 32 + q * 8);
    }
    __syncthreads();

    if (bx < NL0) {
        // =============== layer-0 blocks ===============
        const int n = bx * 16 + r16;
        const float bi = b0c[n], bg = b0c[2 * H_ + n], bo = b0c[3 * H_ + n];
        for (int t = 0; t < T_; ++t) {
            wait_flags(flagsL1, NL1, t);              // need h(t-1)
            floatx4 ai = {0.f,0.f,0.f,0.f}, ag = ai, ao = ai;
            {   // h-part (overlaps est blocks' work)
                const unsigned short* aB = hbf + (m0 + r16) * H_ + q * 8;
                #pragma unroll 4
                for (int k = 8; k < KS0; ++k) {
                    short8 a = *(const short8*)(aB + (k - 8) * 32);
                    ai = __builtin_amdgcn_mfma_f32_16x16x32_bf16(a, *(const short8*)(lfrag + (0*KS0 + k)*512), ai, 0,0,0);
                    ag = __builtin_amdgcn_mfma_f32_16x16x32_bf16(a, *(const short8*)(lfrag + (1*KS0 + k)*512), ag, 0,0,0);
                    ao = __builtin_amdgcn_mfma_f32_16x16x32_bf16(a, *(const short8*)(lfrag + (2*KS0 + k)*512), ao, 0,0,0);
                }
            }
            wait_flags(flagsEst, NEST, t + 1);        // need imputed(t)
            {   // imputed part + activation
                const unsigned short* aB = impbf + (m0 + r16) * D_ + q * 8;
                #pragma unroll
                for (int k = 0; k < 8; ++k) {
                    short8 a = *(const short8*)(aB + k * 32);
                    ai = __builtin_amdgcn_mfma_f32_16x16x32_bf16(a, *(const short8*)(lfrag + (0*KS0 + k)*512), ai, 0,0,0);
                    ag = __builtin_amdgcn_mfma_f32_16x16x32_bf16(a, *(const short8*)(lfrag + (1*KS0 + k)*512), ag, 0,0,0);
                    ao = __builtin_amdgcn_mfma_f32_16x16x32_bf16(a, *(const short8*)(lfrag + (2*KS0 + k)*512), ao, 0,0,0);
                }
                #pragma unroll
                for (int r = 0; r < 4; r++) {
                    int bb = m0 + q * 4 + r;
                    float c = sigmoidf_(ai[r] + bi) * tanhf(ag[r] + bg);
                    float h = sigmoidf_(ao[r] + bo) * tanhf(c);
                    st_short_sc(&h0bf[bb * H_ + n], (unsigned)f2bf(h));
                }
            }
            wave_drain();
            signal_flag(&flagsL0[bx], t + 1);
        }
    } else if (bx < NL0 + NL1) {
        // =============== layer-1 blocks ===============
        const int j = bx - NL0;
        const int n = j * 16 + r16;
        const float bi = b1c[n], bg = b1c[2 * H_ + n], bo = b1c[3 * H_ + n];
        for (int t = 0; t < T_; ++t) {
            wait_flags(flagsL0, NL0, t + 1);          // need h0(t)
            floatx4 li = {0.f,0.f,0.f,0.f}, lg = li, lo = li;
            const unsigned short* aB = h0bf + (m0 + r16) * H_ + q * 8;
            #pragma unroll 4
            for (int k = 0; k < KS1; ++k) {
                short8 a = *(const short8*)(aB + k * 32);
                li = __builtin_amdgcn_mfma_f32_16x16x32_bf16(a, *(const short8*)(lfrag + (0*KS1 + k)*512), li, 0,0,0);
                lg = __builtin_amdgcn_mfma_f32_16x16x32_bf16(a, *(const short8*)(lfrag + (1*KS1 + k)*512), lg, 0,0,0);
                lo = __builtin_amdgcn_mfma_f32_16x16x32_bf16(a, *(const short8*)(lfrag + (2*KS1 + k)*512), lo, 0,0,0);
            }
            #pragma unroll
            for (int r = 0; r < 4; r++) {
                int bb = m0 + q * 4 + r;
                float c = sigmoidf_(li[r] + bi) * tanhf(lg[r] + bg);
                float h = sigmoidf_(lo[r] + bo) * tanhf(c);
                st_short_sc(&hbf[bb * H_ + n], (unsigned)f2bf(h));
                if (t == T_ - 1) out[(size_t)B_ * T_ * D_ + bb * H_ + n] = h;
            }
            wave_drain();
            signal_flag(&flagsL1[j], t + 1);
        }
    } else {
        // =============== est/impute blocks ===============
        const int e  = bx - NL0 - NL1;
        const int dd = e * 16 + r16;
        const float bo_ = bout[dd];
        for (int t = 0; t < T_; ++t) {
            // prefetch X/Mm for this step BEFORE waiting (independent of h)
            float xv[4], mv[4];
            #pragma unroll
            for (int r = 0; r < 4; r++) {
                int bb = m0 + q * 4 + r;
                xv[r] = X [(bb * T_ + t) * D_ + dd];
                mv[r] = Mm[(bb * T_ + t) * D_ + dd];
            }
            asm volatile("" ::: "memory");            // pin prefetch before wait
            wait_flags(flagsL1, NL1, t);              // need h(t-1)
            floatx4 acc = {0.f,0.f,0.f,0.f};
            const unsigned short* aB = hbf + (m0 + r16) * H_ + q * 8;
            #pragma unroll 4
            for (int k = 0; k < KSE; ++k) {
                short8 a = *(const short8*)(aB + k * 32);
                acc = __builtin_amdgcn_mfma_f32_16x16x32_bf16(a, *(const short8*)(lfrag + k*512), acc, 0,0,0);
            }
            #pragma unroll
            for (int r = 0; r < 4; r++) {
                int bb = m0 + q * 4 + r;
                float est = acc[r] + bo_;
                st_short_sc(&impbf[bb * D_ + dd],
                            (unsigned)f2bf(mv[r] * xv[r] + (1.0f - mv[r]) * est));
                if (t >= 1) out[(bb * T_ + (t - 1)) * D_ + dd] = est;
            }
            wave_drain();
            signal_flag(&flagsEst[e], t + 1);
        }
        // final projection: est from h(T-1) -> out[:, T-1, :]
        wait_flags(flagsL1, NL1, T_);
        floatx4 acc = {0.f,0.f,0.f,0.f};
        const unsigned short* aB = hbf + (m0 + r16) * H_ + q * 8;
        #pragma unroll 4
        for (int k = 0; k < KSE; ++k) {
            short8 a = *(const short8*)(aB + k * 32);
            acc = __builtin_amdgcn_mfma_f32_16x16x32_bf16(a, *(const short8*)(lfrag + k*512), acc, 0,0,0);
        }
        #pragma unroll
        for (int r = 0; r < 4; r++) {
            int bb = m0 + q * 4 + r;
            out[(bb * T_ + (T_ - 1)) * D_ + dd] = acc[r] + bo_;
        }
    }
}

extern "C" void kernel_launch(void* const* d_in, const int* in_sizes, int n_in,
                              void* d_out, int out_size, void* d_ws, size_t ws_size,
                              hipStream_t stream) {
    const float* X    = (const float*)d_in[0];
    const float* Mm   = (const float*)d_in[1];
    const float* Wih0 = (const float*)d_in[2];
    const float* Whh0 = (const float*)d_in[3];
    const float* bih0 = (const float*)d_in[4];
    const float* bhh0 = (const float*)d_in[5];
    const float* Wih1 = (const float*)d_in[6];
    const float* Whh1 = (const float*)d_in[7];
    const float* bih1 = (const float*)d_in[8];
    const float* bhh1 = (const float*)d_in[9];
    const float* Wout = (const float*)d_in[10];
    const float* bout = (const float*)d_in[11];
    float* out = (float*)d_out;

    char* ws = (char*)d_ws;
    size_t off = 0;
    auto alloc = [&](size_t bytes) { char* p = ws + off; off = (off + bytes + 255) & ~(size_t)255; return p; };
    int*            flagsL1  = (int*)alloc(NL1 * 4);
    int*            flagsEst = (int*)alloc(NEST * 4);
    int*            flagsL0  = (int*)alloc(NL0 * 4);
    unsigned short* hbf    = (unsigned short*)alloc(B_ * H_ * 2);
    unsigned short* h0bf   = (unsigned short*)alloc(B_ * H_ * 2);
    unsigned short* impbf  = (unsigned short*)alloc(B_ * D_ * 2);
    unsigned short* Wih0bf = (unsigned short*)alloc((size_t)G_ * D_ * 2);
    unsigned short* Whh0bf = (unsigned short*)alloc((size_t)G_ * H_ * 2);
    unsigned short* W1bf   = (unsigned short*)alloc((size_t)G_ * H_ * 2);
    unsigned short* Woutbf = (unsigned short*)alloc((size_t)D_ * H_ * 2);
    float*          b0c    = (float*)alloc(G_ * 4);
    float*          b1c    = (float*)alloc(G_ * 4);

    (void)hipMemsetAsync(flagsL1, 0, (char*)hbf - (char*)flagsL1, stream);  // all flags
    (void)hipMemsetAsync(hbf, 0, B_ * H_ * 2, stream);

    {
        int n;
        n = G_ * D_; k_cvt   <<<(n + 255) / 256, 256, 0, stream>>>(Wih0, Wih0bf, n);
        n = G_ * H_; k_cvt   <<<(n + 255) / 256, 256, 0, stream>>>(Whh0, Whh0bf, n);
        n = G_ * H_; k_addcvt<<<(n + 255) / 256, 256, 0, stream>>>(Wih1, Whh1, W1bf, n);
        n = D_ * H_; k_cvt   <<<(n + 255) / 256, 256, 0, stream>>>(Wout, Woutbf, n);
        n = G_;      k_addf  <<<(n + 255) / 256, 256, 0, stream>>>(bih0, bhh0, b0c, n);
        n = G_;      k_addf  <<<(n + 255) / 256, 256, 0, stream>>>(bih1, bhh1, b1c, n);
    }

    k_fused<<<NBLK, 256, 0, stream>>>(Wih0bf, Whh0bf, W1bf, Woutbf, b0c, b1c, bout,
                                      X, Mm, hbf, h0bf, impbf, out,
                                      flagsL1, flagsEst, flagsL0);
}

// Round 6
// 2928.014 us; speedup vs baseline: 3.4323x; 1.0854x over previous
//
#include <hip/hip_runtime.h>
#include <math.h>

// MultiRNNCell: 2-layer LSTM-imputation scan. B=64, T=128, D=256, H=1024.
// R5: fully fence-free cross-block dataflow.
//  - producers: sc0 sc1 write-through stores -> MALL, per-wave vmcnt(0),
//    relaxed agent flag store (no release fence, no wbl2)
//  - consumers: NO acquire fence / NO buffer_inv. All stale-prone buffers
//    (hbf/h0bf/impbf) read via batched `global_load_dwordx4 ... sc0 sc1`
//    preloads (imm offsets) + one vmcnt(0) per phase. L2 stays warm for
//    read-only X/Mm.
//  - est + final projection use 2-way split accumulator chains (MFMA latency)
//  - `out` stores moved after the signal (off critical path)
// 144 blocks x 256 thr, 120KB LDS -> 1 block/CU, all co-resident.
// Dead forget gate removed; layer1 weight fold W1 = Wih1+Whh1.

#define B_ 64
#define T_ 128
#define D_ 256
#define H_ 1024
#define G_ 4096

#define NL0 64
#define NL1 64
#define NEST 16
#define NBLK (NL0 + NL1 + NEST)   // 144

#define KS0 40          // layer0 ksteps: 8 (imputed, D=256) + 32 (h, H=1024)
#define KS1 32          // layer1 ksteps (H=1024)
#define KSE 32          // est ksteps (H=1024)

typedef __attribute__((ext_vector_type(8))) short short8;   // 8 bf16
typedef __attribute__((ext_vector_type(4))) float floatx4;  // MFMA C/D

__device__ __forceinline__ unsigned short f2bf(float x) {
    union { float f; unsigned u; } v; v.f = x;
    unsigned r = v.u + 0x7fffu + ((v.u >> 16) & 1u);  // RNE
    return (unsigned short)(r >> 16);
}
__device__ __forceinline__ float sigmoidf_(float x) { return 1.0f / (1.0f + expf(-x)); }

// write-through 2B store to the MALL coherence point (bypasses L1+L2)
__device__ __forceinline__ void st_short_sc(unsigned short* p, unsigned v) {
    asm volatile("global_store_short %0, %1, off sc0 sc1"
                 :: "v"(p), "v"(v) : "memory");
}
__device__ __forceinline__ void vm_drain() {
    asm volatile("s_waitcnt vmcnt(0)" ::: "memory");
}

// batched always-fresh 16B loads: issue N loads with immediate offsets from a
// per-lane base, then one vmcnt(0); "touch" pins uses after the drain.
#define LOADK(arr, base, N)                                                    \
    _Pragma("unroll")                                                          \
    for (int _k = 0; _k < (N); ++_k)                                           \
        asm volatile("global_load_dwordx4 %0, %1, off offset:%c2 sc0 sc1"      \
                     : "=v"((arr)[_k]) : "v"(base), "i"(_k * 64));             \
    vm_drain();                                                                \
    _Pragma("unroll")                                                          \
    for (int _k = 0; _k < (N); ++_k)                                           \
        asm volatile("" : "+v"((arr)[_k]));

// ---------------- prep kernels ----------------
__global__ void k_cvt(const float* __restrict__ s, unsigned short* __restrict__ d, int n) {
    int i = blockIdx.x * 256 + threadIdx.x;
    if (i < n) d[i] = f2bf(s[i]);
}
__global__ void k_addcvt(const float* __restrict__ a, const float* __restrict__ b,
                         unsigned short* __restrict__ d, int n) {
    int i = blockIdx.x * 256 + threadIdx.x;
    if (i < n) d[i] = f2bf(a[i] + b[i]);
}
__global__ void k_addf(const float* __restrict__ a, const float* __restrict__ b,
                       float* __restrict__ d, int n) {
    int i = blockIdx.x * 256 + threadIdx.x;
    if (i < n) d[i] = a[i] + b[i];
}

// ---------------- producer/consumer sync ----------------
// Wave 0 polls relaxed agent (sc1 -> always fresh from MALL). No acquire
// fence: data reads are sc1 themselves. Rare periodic fence = livelock
// insurance only.
__device__ __forceinline__ void wait_flags(int* flags, int P, int target) {
    if (threadIdx.x < 64) {
        if (threadIdx.x < (unsigned)P) {
            int spins = 0;
            while (__hip_atomic_load(flags + threadIdx.x, __ATOMIC_RELAXED,
                                     __HIP_MEMORY_SCOPE_AGENT) < target) {
                if ((++spins & 2047) == 0)
                    __builtin_amdgcn_fence(__ATOMIC_ACQUIRE, "agent");
            }
        }
    }
    __syncthreads();
}
// Producer data already at MALL (sc1 stores + per-wave vmcnt drain before the
// barrier). Flag store relaxed agent (sc1 write-through). No release fence.
__device__ __forceinline__ void signal_flag(int* flag, int val) {
    __syncthreads();
    if (threadIdx.x == 0)
        __hip_atomic_store(flag, val, __ATOMIC_RELAXED, __HIP_MEMORY_SCOPE_AGENT);
}

// ---------------- fused persistent kernel ----------------
__global__ __launch_bounds__(256, 1) void k_fused(
    const unsigned short* __restrict__ Wih0bf, const unsigned short* __restrict__ Whh0bf,
    const unsigned short* __restrict__ W1bf,   const unsigned short* __restrict__ Woutbf,
    const float* __restrict__ b0c, const float* __restrict__ b1c, const float* __restrict__ bout,
    const float* __restrict__ X, const float* __restrict__ Mm,
    unsigned short* __restrict__ hbf, unsigned short* __restrict__ h0bf,
    unsigned short* __restrict__ impbf, float* __restrict__ out,
    int* __restrict__ flagsL1, int* __restrict__ flagsEst, int* __restrict__ flagsL0)
{
    // weight fragments: [fragIdx][lane][8 bf16]; ds_read_b128 conflict-free
    __shared__ unsigned short ldsW[3 * KS0 * 64 * 8];   // 120 KB (l0 blocks)

    const int tid  = threadIdx.x;
    const int lane = tid & 63;
    const int wv   = tid >> 6;       // wave id = m-tile (16 batch rows)
    const int r16  = lane & 15, q = lane >> 4;
    const int bx   = blockIdx.x;
    const int m0   = wv * 16;
    const unsigned short* lfrag = ldsW + lane * 8;   // + fragIdx*512

    // ---- one-time: rearrange weights into LDS fragment order ----
    if (bx < NL0) {
        int n0 = bx * 16;
        for (int idx = wv; idx < 3 * KS0; idx += 4) {
            int gi = idx / KS0, k = idx % KS0;
            int grow = (gi == 0) ? 0 : (gi == 1 ? 2 * H_ : 3 * H_);
            const unsigned short* src = (k < 8)
                ? Wih0bf + (grow + n0 + r16) * D_ + k * 32 + q * 8
                : Whh0bf + (grow + n0 + r16) * H_ + (k - 8) * 32 + q * 8;
            *(short8*)(ldsW + ((size_t)idx * 64 + lane) * 8) = *(const short8*)src;
        }
    } else if (bx < NL0 + NL1) {
        int n0 = (bx - NL0) * 16;
        for (int idx = wv; idx < 3 * KS1; idx += 4) {
            int gi = idx / KS1, k = idx % KS1;
            int grow = (gi == 0) ? 0 : (gi == 1 ? 2 * H_ : 3 * H_);
            *(short8*)(ldsW + ((size_t)idx * 64 + lane) * 8) =
                *(const short8*)(W1bf + (grow + n0 + r16) * H_ + k * 32 + q * 8);
        }
    } else {
        int d0 = (bx - NL0 - NL1) * 16;
        for (int idx = wv; idx < KSE; idx += 4)
            *(short8*)(ldsW + ((size_t)idx * 64 + lane) * 8) =
                *(const short8*)(Woutbf + (d0 + r16) * H_ + idx * 32 + q * 8);
    }
    __syncthreads();

    if (bx < NL0) {
        // =============== layer-0 blocks ===============
        const int n = bx * 16 + r16;
        const float bi = b0c[n], bg = b0c[2 * H_ + n], bo = b0c[3 * H_ + n];
        const unsigned short* hB = hbf   + (m0 + r16) * H_ + q * 8;
        const unsigned short* iB = impbf + (m0 + r16) * D_ + q * 8;
        for (int t = 0; t < T_; ++t) {
            wait_flags(flagsL1, NL1, t);              // need h(t-1)
            floatx4 ai = {0.f,0.f,0.f,0.f}, ag = ai, ao = ai;
            {   // h-part (overlaps est blocks' work)
                short8 ah[32];
                LOADK(ah, hB, 32);
                #pragma unroll
                for (int k = 0; k < 32; ++k) {
                    ai = __builtin_amdgcn_mfma_f32_16x16x32_bf16(ah[k], *(const short8*)(lfrag + (0*KS0 + k + 8)*512), ai, 0,0,0);
                    ag = __builtin_amdgcn_mfma_f32_16x16x32_bf16(ah[k], *(const short8*)(lfrag + (1*KS0 + k + 8)*512), ag, 0,0,0);
                    ao = __builtin_amdgcn_mfma_f32_16x16x32_bf16(ah[k], *(const short8*)(lfrag + (2*KS0 + k + 8)*512), ao, 0,0,0);
                }
            }
            wait_flags(flagsEst, NEST, t + 1);        // need imputed(t)
            {   // imputed part + activation
                short8 am[8];
                LOADK(am, iB, 8);
                #pragma unroll
                for (int k = 0; k < 8; ++k) {
                    ai = __builtin_amdgcn_mfma_f32_16x16x32_bf16(am[k], *(const short8*)(lfrag + (0*KS0 + k)*512), ai, 0,0,0);
                    ag = __builtin_amdgcn_mfma_f32_16x16x32_bf16(am[k], *(const short8*)(lfrag + (1*KS0 + k)*512), ag, 0,0,0);
                    ao = __builtin_amdgcn_mfma_f32_16x16x32_bf16(am[k], *(const short8*)(lfrag + (2*KS0 + k)*512), ao, 0,0,0);
                }
                #pragma unroll
                for (int r = 0; r < 4; r++) {
                    int bb = m0 + q * 4 + r;
                    float c = sigmoidf_(ai[r] + bi) * tanhf(ag[r] + bg);
                    float h = sigmoidf_(ao[r] + bo) * tanhf(c);
                    st_short_sc(&h0bf[bb * H_ + n], (unsigned)f2bf(h));
                }
            }
            vm_drain();
            signal_flag(&flagsL0[bx], t + 1);
        }
    } else if (bx < NL0 + NL1) {
        // =============== layer-1 blocks ===============
        const int j = bx - NL0;
        const int n = j * 16 + r16;
        const float bi = b1c[n], bg = b1c[2 * H_ + n], bo = b1c[3 * H_ + n];
        const unsigned short* aB = h0bf + (m0 + r16) * H_ + q * 8;
        for (int t = 0; t < T_; ++t) {
            wait_flags(flagsL0, NL0, t + 1);          // need h0(t)
            floatx4 li = {0.f,0.f,0.f,0.f}, lg = li, lo = li;
            short8 ah[32];
            LOADK(ah, aB, 32);
            #pragma unroll
            for (int k = 0; k < 32; ++k) {
                li = __builtin_amdgcn_mfma_f32_16x16x32_bf16(ah[k], *(const short8*)(lfrag + (0*KS1 + k)*512), li, 0,0,0);
                lg = __builtin_amdgcn_mfma_f32_16x16x32_bf16(ah[k], *(const short8*)(lfrag + (1*KS1 + k)*512), lg, 0,0,0);
                lo = __builtin_amdgcn_mfma_f32_16x16x32_bf16(ah[k], *(const short8*)(lfrag + (2*KS1 + k)*512), lo, 0,0,0);
            }
            float hv[4];
            #pragma unroll
            for (int r = 0; r < 4; r++) {
                int bb = m0 + q * 4 + r;
                float c = sigmoidf_(li[r] + bi) * tanhf(lg[r] + bg);
                hv[r] = sigmoidf_(lo[r] + bo) * tanhf(c);
                st_short_sc(&hbf[bb * H_ + n], (unsigned)f2bf(hv[r]));
            }
            vm_drain();
            signal_flag(&flagsL1[j], t + 1);
            if (t == T_ - 1) {
                #pragma unroll
                for (int r = 0; r < 4; r++) {
                    int bb = m0 + q * 4 + r;
                    out[(size_t)B_ * T_ * D_ + bb * H_ + n] = hv[r];
                }
            }
        }
    } else {
        // =============== est/impute blocks ===============
        const int e  = bx - NL0 - NL1;
        const int dd = e * 16 + r16;
        const float bo_ = bout[dd];
        const unsigned short* aB = hbf + (m0 + r16) * H_ + q * 8;
        for (int t = 0; t < T_; ++t) {
            // prefetch X/Mm for this step BEFORE waiting (read-only, L2-warm)
            float xv[4], mv[4];
            #pragma unroll
            for (int r = 0; r < 4; r++) {
                int bb = m0 + q * 4 + r;
                xv[r] = X [(bb * T_ + t) * D_ + dd];
                mv[r] = Mm[(bb * T_ + t) * D_ + dd];
            }
            asm volatile("" ::: "memory");            // pin prefetch before wait
            wait_flags(flagsL1, NL1, t);              // need h(t-1)
            floatx4 a0 = {0.f,0.f,0.f,0.f}, a1 = a0;  // 2-way acc chain split
            short8 ah[32];
            LOADK(ah, aB, 32);
            #pragma unroll
            for (int k = 0; k < 16; ++k) {
                a0 = __builtin_amdgcn_mfma_f32_16x16x32_bf16(ah[2*k  ], *(const short8*)(lfrag + (2*k  )*512), a0, 0,0,0);
                a1 = __builtin_amdgcn_mfma_f32_16x16x32_bf16(ah[2*k+1], *(const short8*)(lfrag + (2*k+1)*512), a1, 0,0,0);
            }
            float estv[4];
            #pragma unroll
            for (int r = 0; r < 4; r++) {
                int bb = m0 + q * 4 + r;
                estv[r] = a0[r] + a1[r] + bo_;
                st_short_sc(&impbf[bb * D_ + dd],
                            (unsigned)f2bf(mv[r] * xv[r] + (1.0f - mv[r]) * estv[r]));
            }
            vm_drain();
            signal_flag(&flagsEst[e], t + 1);
            if (t >= 1) {
                #pragma unroll
                for (int r = 0; r < 4; r++) {
                    int bb = m0 + q * 4 + r;
                    out[(bb * T_ + (t - 1)) * D_ + dd] = estv[r];
                }
            }
        }
        // final projection: est from h(T-1) -> out[:, T-1, :]
        wait_flags(flagsL1, NL1, T_);
        floatx4 a0 = {0.f,0.f,0.f,0.f}, a1 = a0;
        short8 ah[32];
        LOADK(ah, aB, 32);
        #pragma unroll
        for (int k = 0; k < 16; ++k) {
            a0 = __builtin_amdgcn_mfma_f32_16x16x32_bf16(ah[2*k  ], *(const short8*)(lfrag + (2*k  )*512), a0, 0,0,0);
            a1 = __builtin_amdgcn_mfma_f32_16x16x32_bf16(ah[2*k+1], *(const short8*)(lfrag + (2*k+1)*512), a1, 0,0,0);
        }
        #pragma unroll
        for (int r = 0; r < 4; r++) {
            int bb = m0 + q * 4 + r;
            out[(bb * T_ + (T_ - 1)) * D_ + dd] = a0[r] + a1[r] + bo_;
        }
    }
}

extern "C" void kernel_launch(void* const* d_in, const int* in_sizes, int n_in,
                              void* d_out, int out_size, void* d_ws, size_t ws_size,
                              hipStream_t stream) {
    const float* X    = (const float*)d_in[0];
    const float* Mm   = (const float*)d_in[1];
    const float* Wih0 = (const float*)d_in[2];
    const float* Whh0 = (const float*)d_in[3];
    const float* bih0 = (const float*)d_in[4];
    const float* bhh0 = (const float*)d_in[5];
    const float* Wih1 = (const float*)d_in[6];
    const float* Whh1 = (const float*)d_in[7];
    const float* bih1 = (const float*)d_in[8];
    const float* bhh1 = (const float*)d_in[9];
    const float* Wout = (const float*)d_in[10];
    const float* bout = (const float*)d_in[11];
    float* out = (float*)d_out;

    char* ws = (char*)d_ws;
    size_t off = 0;
    auto alloc = [&](size_t bytes) { char* p = ws + off; off = (off + bytes + 255) & ~(size_t)255; return p; };
    int*            flagsL1  = (int*)alloc(NL1 * 4);
    int*            flagsEst = (int*)alloc(NEST * 4);
    int*            flagsL0  = (int*)alloc(NL0 * 4);
    unsigned short* hbf    = (unsigned short*)alloc(B_ * H_ * 2);
    unsigned short* h0bf   = (unsigned short*)alloc(B_ * H_ * 2);
    unsigned short* impbf  = (unsigned short*)alloc(B_ * D_ * 2);
    unsigned short* Wih0bf = (unsigned short*)alloc((size_t)G_ * D_ * 2);
    unsigned short* Whh0bf = (unsigned short*)alloc((size_t)G_ * H_ * 2);
    unsigned short* W1bf   = (unsigned short*)alloc((size_t)G_ * H_ * 2);
    unsigned short* Woutbf = (unsigned short*)alloc((size_t)D_ * H_ * 2);
    float*          b0c    = (float*)alloc(G_ * 4);
    float*          b1c    = (float*)alloc(G_ * 4);

    (void)hipMemsetAsync(flagsL1, 0, (char*)hbf - (char*)flagsL1, stream);  // all flags
    (void)hipMemsetAsync(hbf, 0, B_ * H_ * 2, stream);

    {
        int n;
        n = G_ * D_; k_cvt   <<<(n + 255) / 256, 256, 0, stream>>>(Wih0, Wih0bf, n);
        n = G_ * H_; k_cvt   <<<(n + 255) / 256, 256, 0, stream>>>(Whh0, Whh0bf, n);
        n = G_ * H_; k_addcvt<<<(n + 255) / 256, 256, 0, stream>>>(Wih1, Whh1, W1bf, n);
        n = D_ * H_; k_cvt   <<<(n + 255) / 256, 256, 0, stream>>>(Wout, Woutbf, n);
        n = G_;      k_addf  <<<(n + 255) / 256, 256, 0, stream>>>(bih0, bhh0, b0c, n);
        n = G_;      k_addf  <<<(n + 255) / 256, 256, 0, stream>>>(bih1, bhh1, b1c, n);
    }

    k_fused<<<NBLK, 256, 0, stream>>>(Wih0bf, Whh0bf, W1bf, Woutbf, b0c, b1c, bout,
                                      X, Mm, hbf, h0bf, impbf, out,
                                      flagsL1, flagsEst, flagsL0);
}